// Round 3
// baseline (2440.130 us; speedup 1.0000x reference)
//
#include <hip/hip_runtime.h>

#define ALPHA_C 0.1f
#define EPS_C 1e-4f

// ---------- degree count: deg[dst[e]] += 1 ----------
__global__ __launch_bounds__(256) void count_deg_kernel(const int* __restrict__ dst, int E,
                                                        float* __restrict__ deg) {
  int i = blockIdx.x * 256 + threadIdx.x;
  if (i < E) unsafeAtomicAdd(&deg[dst[i]], 1.0f);
}

__global__ __launch_bounds__(256) void invert_deg_kernel(float* __restrict__ deg, int n) {
  int i = blockIdx.x * 256 + threadIdx.x;
  if (i < n) deg[i] = 1.0f / (deg[i] + EPS_C);
}

// ---------- GEMM + ReLU: out[M,128] = relu(in[M,128] @ W[128,128]), all f32 ----------
// 256 threads, 64 rows/block. LDS: A-tile 32KB + W-half 32KB = 64KB.
// Thread (c4 = t&31, rg = t>>5) owns rows rg*8..rg*8+7, cols 4*c4..4*c4+3.
__global__ __launch_bounds__(256) void gemm_relu_kernel(const float* __restrict__ inp,
                                                        const float* __restrict__ Wg,
                                                        float* __restrict__ out, int M) {
  __shared__ float Al[64 * 128];
  __shared__ float Wl[64 * 128];
  const int t = threadIdx.x;
  const int row0 = blockIdx.x * 64;
  const float4* A4 = (const float4*)inp;
  const float4* Wg4 = (const float4*)Wg;
  float4* Al4 = (float4*)Al;
  float4* Wl4 = (float4*)Wl;

  // stage A tile: 64 rows x 128 f32 = 2048 float4, coalesced
#pragma unroll
  for (int i = 0; i < 8; ++i) {
    int idx = i * 256 + t;
    int r = idx >> 5;  // local row
    float4 v = make_float4(0.f, 0.f, 0.f, 0.f);
    if (row0 + r < M) v = A4[(size_t)row0 * 32 + idx];
    Al4[idx] = v;
  }

  const int c4 = t & 31;
  const int rg = t >> 5;
  float4 acc[8];
#pragma unroll
  for (int rr = 0; rr < 8; ++rr) acc[rr] = make_float4(0.f, 0.f, 0.f, 0.f);

  for (int half = 0; half < 2; ++half) {
    __syncthreads();  // iter0: A-writes vs reads; iter1: Wl reuse vs prior reads
#pragma unroll
    for (int i = 0; i < 8; ++i) {
      int idx = i * 256 + t;
      Wl4[idx] = Wg4[half * 2048 + idx];  // rows half*64.., contiguous
    }
    __syncthreads();

#pragma unroll 4
    for (int k4 = 0; k4 < 16; ++k4) {
      float ar[8][4];
#pragma unroll
      for (int rr = 0; rr < 8; ++rr) {
        float4 a = Al4[(rg * 8 + rr) * 32 + half * 16 + k4];
        ar[rr][0] = a.x; ar[rr][1] = a.y; ar[rr][2] = a.z; ar[rr][3] = a.w;
      }
#pragma unroll
      for (int kk = 0; kk < 4; ++kk) {
        float4 w = Wl4[(k4 * 4 + kk) * 32 + c4];
#pragma unroll
        for (int rr = 0; rr < 8; ++rr) {
          acc[rr].x += ar[rr][kk] * w.x;
          acc[rr].y += ar[rr][kk] * w.y;
          acc[rr].z += ar[rr][kk] * w.z;
          acc[rr].w += ar[rr][kk] * w.w;
        }
      }
    }
  }

#pragma unroll
  for (int rr = 0; rr < 8; ++rr) {
    int r = row0 + rg * 8 + rr;
    if (r < M) {
      float4 o;
      o.x = fmaxf(acc[rr].x, 0.f);
      o.y = fmaxf(acc[rr].y, 0.f);
      o.z = fmaxf(acc[rr].z, 0.f);
      o.w = fmaxf(acc[rr].w, 0.f);
      ((float4*)out)[(size_t)r * 32 + c4] = o;
    }
  }
}

// ---------- edge aggregation: acc[dst] += h[src] * invdeg[dst] ----------
// one wave (64 lanes) per edge, float2 per lane
__global__ __launch_bounds__(256) void agg_kernel(const int* __restrict__ src,
                                                  const int* __restrict__ dst, int E,
                                                  const float* __restrict__ h,
                                                  const float* __restrict__ invdeg,
                                                  float* __restrict__ acc) {
  long gid = (long)blockIdx.x * 256 + threadIdx.x;
  int e = (int)(gid >> 6);
  if (e >= E) return;
  int lane = (int)(gid & 63);
  int s = src[e], d = dst[e];
  float w = invdeg[d];
  float2 v = ((const float2*)(h + (size_t)s * 128))[lane];
  float* ar = acc + (size_t)d * 128 + lane * 2;
  unsafeAtomicAdd(ar, v.x * w);
  unsafeAtomicAdd(ar + 1, v.y * w);
}

// ---------- combine: dst = (alpha*halpha + gsum) * inv_cnt ----------
__global__ __launch_bounds__(256) void combine_kernel(float* __restrict__ dstb,
                                                      const float* __restrict__ halpha,
                                                      const float* __restrict__ gsum,
                                                      float inv_cnt, int n4) {
  int i = blockIdx.x * 256 + threadIdx.x;
  if (i >= n4) return;
  float4 h = ((const float4*)halpha)[i];
  float4 g = ((const float4*)gsum)[i];
  float4 o;
  o.x = (ALPHA_C * h.x + g.x) * inv_cnt;
  o.y = (ALPHA_C * h.y + g.y) * inv_cnt;
  o.z = (ALPHA_C * h.z + g.z) * inv_cnt;
  o.w = (ALPHA_C * h.w + g.w) * inv_cnt;
  ((float4*)dstb)[i] = o;
}

// ---------- final: out[M,16] = hp[M,128] @ Wout[128,16] + b, all f32 ----------
__global__ __launch_bounds__(256) void final_kernel(const float* __restrict__ hp,
                                                    const float* __restrict__ Wo,
                                                    const float* __restrict__ bo,
                                                    float* __restrict__ out, int M) {
  __shared__ float Wl[128 * 16];
  __shared__ float bl[16];
  int t = threadIdx.x;
#pragma unroll
  for (int i = 0; i < 8; ++i) Wl[i * 256 + t] = Wo[i * 256 + t];
  if (t < 16) bl[t] = bo[t];
  __syncthreads();

  int c4 = t & 3;  // col group of 4 (16 cols total)
  long row = (long)blockIdx.x * 64 + (t >> 2);
  if (row >= M) return;
  const float4* a4 = (const float4*)(hp + row * 128);
  const float4* Wl4 = (const float4*)Wl;
  float4 acc = make_float4(0.f, 0.f, 0.f, 0.f);
#pragma unroll 4
  for (int k4 = 0; k4 < 32; ++k4) {
    float4 a = a4[k4];
    float av[4] = {a.x, a.y, a.z, a.w};
#pragma unroll
    for (int kk = 0; kk < 4; ++kk) {
      float4 w = Wl4[(k4 * 4 + kk) * 4 + c4];
      acc.x += av[kk] * w.x;
      acc.y += av[kk] * w.y;
      acc.z += av[kk] * w.z;
      acc.w += av[kk] * w.w;
    }
  }
  acc.x += bl[c4 * 4 + 0];
  acc.y += bl[c4 * 4 + 1];
  acc.z += bl[c4 * 4 + 2];
  acc.w += bl[c4 * 4 + 3];
  ((float4*)out)[row * 4 + c4] = acc;
}

extern "C" void kernel_launch(void* const* d_in, const int* in_sizes, int n_in,
                              void* d_out, int out_size, void* d_ws, size_t ws_size,
                              hipStream_t stream) {
  const float* x_paper = (const float*)d_in[0];
  const float* x_author = (const float*)d_in[1];
  // d_in[2] x_field: DEAD (fields never feed papers/authors; output = papers only)
  const float* Wp0 = (const float*)d_in[3];
  const float* Wp1 = (const float*)d_in[4];
  const float* Wa0 = (const float*)d_in[5];
  const float* Wa1 = (const float*)d_in[6];
  // d_in[7] W_field_0, d_in[8] W_field_1: DEAD
  const float* Wout = (const float*)d_in[9];
  const float* bout = (const float*)d_in[10];
  const int* src_w = (const int*)d_in[11];
  const int* dst_w = (const int*)d_in[12];
  const int* src_b = (const int*)d_in[13];
  const int* dst_b = (const int*)d_in[14];
  const int* src_c = (const int*)d_in[15];
  const int* dst_c = (const int*)d_in[16];
  // d_in[17]/d_in[18] topic edges: DEAD

  const int NP = in_sizes[0] / 128, NA = in_sizes[1] / 128;
  const int EW = in_sizes[11], EB = in_sizes[13], EC = in_sizes[15];

  // workspace layout (all f32): ~155 MB total.
  float* hp = (float*)d_ws;               // [NP,128] paper h
  float* ha = hp + (size_t)NP * 128;      // [NA,128] author h
  float* gp = ha + (size_t)NA * 128;      // [NP,128] paper acc / post-L1
  float* ga = gp + (size_t)NP * 128;      // [NA,128] author acc / post-L1
  float* idw = ga + (size_t)NA * 128;     // invdeg writes->paper [NP]
  float* idc = idw + NP;                  // invdeg cites->paper  [NP]
  float* ida = idc + NP;                  // invdeg wb->author    [NA]

  dim3 B(256);
  auto cdiv = [](long a, long b) { return (int)((a + b - 1) / b); };

  // ---- degrees (layer-invariant, computed once) ----
  hipMemsetAsync(idw, 0, (size_t)(2 * NP + NA) * 4, stream);
  count_deg_kernel<<<cdiv(EW, 256), B, 0, stream>>>(dst_w, EW, idw);
  count_deg_kernel<<<cdiv(EC, 256), B, 0, stream>>>(dst_c, EC, idc);
  count_deg_kernel<<<cdiv(EB, 256), B, 0, stream>>>(dst_b, EB, ida);
  invert_deg_kernel<<<cdiv(2 * NP + NA, 256), B, 0, stream>>>(idw, 2 * NP + NA);

  // ---- layer 0: h = relu(x @ W0) ----
  gemm_relu_kernel<<<cdiv(NP, 64), B, 0, stream>>>(x_paper, Wp0, hp, NP);
  gemm_relu_kernel<<<cdiv(NA, 64), B, 0, stream>>>(x_author, Wa0, ha, NA);

  // ---- layer 0 aggregation (pre-scaled by invdeg; writes+cites share one acc) ----
  hipMemsetAsync(gp, 0, (size_t)(NP + NA) * 128 * 4, stream);
  agg_kernel<<<cdiv((long)EW * 64, 256), B, 0, stream>>>(src_w, dst_w, EW, ha, idw, gp);
  agg_kernel<<<cdiv((long)EC * 64, 256), B, 0, stream>>>(src_c, dst_c, EC, hp, idc, gp);
  agg_kernel<<<cdiv((long)EB * 64, 256), B, 0, stream>>>(src_b, dst_b, EB, hp, ida, ga);

  // ---- layer 0 combine (in place into h buffers) ----
  combine_kernel<<<cdiv((long)NP * 32, 256), B, 0, stream>>>(hp, hp, gp, 1.f / 3.f, NP * 32);
  combine_kernel<<<cdiv((long)NA * 32, 256), B, 0, stream>>>(ha, ha, ga, 0.5f, NA * 32);

  // ---- layer 1 GEMMs ----
  gemm_relu_kernel<<<cdiv(NP, 64), B, 0, stream>>>(hp, Wp1, gp, NP);
  gemm_relu_kernel<<<cdiv(NA, 64), B, 0, stream>>>(ha, Wa1, ga, NA);

  // ---- layer 1 aggregation into hp (reused as paper accumulator) ----
  hipMemsetAsync(hp, 0, (size_t)NP * 128 * 4, stream);
  agg_kernel<<<cdiv((long)EW * 64, 256), B, 0, stream>>>(src_w, dst_w, EW, ga, idw, hp);
  agg_kernel<<<cdiv((long)EC * 64, 256), B, 0, stream>>>(src_c, dst_c, EC, gp, idc, hp);

  // ---- layer 1 combine: hp = (alpha*gp + hp)/3 ----
  combine_kernel<<<cdiv((long)NP * 32, 256), B, 0, stream>>>(hp, gp, hp, 1.f / 3.f, NP * 32);

  // ---- final: out = hp @ W_out + b_out (f32) ----
  final_kernel<<<cdiv(NP, 64), B, 0, stream>>>(hp, Wout, bout, (float*)d_out, NP);
}

// Round 5
// 783.557 us; speedup vs baseline: 3.1142x; 3.1142x over previous
//
#include <hip/hip_runtime.h>

#define ALPHA_C 0.1f
#define EPS_C 1e-4f

// ================= CSR build =================

__global__ __launch_bounds__(256) void count_i_kernel(const int* __restrict__ dst, int E,
                                                      int* __restrict__ cnt) {
  int i = blockIdx.x * 256 + threadIdx.x;
  if (i < E) atomicAdd(&cnt[dst[i]], 1);
}

// pass 1: per-block exclusive scan of cnt into rs (block-local), block totals into bsum
__global__ __launch_bounds__(256) void scan256_kernel(const int* __restrict__ cnt, int n,
                                                      int* __restrict__ rs,
                                                      int* __restrict__ bsum) {
  __shared__ int sm[256];
  int t = threadIdx.x;
  int i = blockIdx.x * 256 + t;
  int v = (i < n) ? cnt[i] : 0;
  sm[t] = v;
  __syncthreads();
  int acc = v;
  for (int off = 1; off < 256; off <<= 1) {
    int add = (t >= off) ? sm[t - off] : 0;
    __syncthreads();
    acc += add;
    sm[t] = acc;
    __syncthreads();
  }
  if (i < n) rs[i] = acc - v;       // block-local exclusive
  if (i == n - 1) rs[n] = acc;      // local grand total at the end slot
  if (t == 255) bsum[blockIdx.x] = acc;
}

// pass 2: single-block exclusive scan of block sums (nb <= 1024)
__global__ __launch_bounds__(1024) void scan_bsums_kernel(int* __restrict__ bsum, int nb) {
  __shared__ int sm[1024];
  int t = threadIdx.x;
  int v = (t < nb) ? bsum[t] : 0;
  sm[t] = v;
  __syncthreads();
  int acc = v;
  for (int off = 1; off < 1024; off <<= 1) {
    int add = (t >= off) ? sm[t - off] : 0;
    __syncthreads();
    acc += add;
    sm[t] = acc;
    __syncthreads();
  }
  if (t < nb) bsum[t] = acc - v;  // exclusive
}

// pass 3: add block offsets (covers rs[0..n] inclusive)
__global__ __launch_bounds__(256) void add_off_kernel(int* __restrict__ rs, int n,
                                                      const int* __restrict__ bsum) {
  int i = blockIdx.x * 256 + threadIdx.x;
  if (i <= n) {
    int b = ((i == n) ? (n - 1) : i) >> 8;
    rs[i] += bsum[b];
  }
}

// scatter edges into CSR col lists via per-dst cursors
__global__ __launch_bounds__(256) void scatter_kernel(const int* __restrict__ src,
                                                      const int* __restrict__ dst, int E,
                                                      const int* __restrict__ rs,
                                                      int* __restrict__ cur,
                                                      int* __restrict__ col) {
  int i = blockIdx.x * 256 + threadIdx.x;
  if (i < E) {
    int d = dst[i];
    int pos = atomicAdd(&cur[d], 1);
    col[rs[d] + pos] = src[i];
  }
}

// ================= GEMM + ReLU: out[M,128] = relu(in[M,128] @ W[128,128]) =================
// 256 threads, 64 rows/block. LDS: A-tile 32KB + W-half 32KB = 64KB.
__global__ __launch_bounds__(256) void gemm_relu_kernel(const float* __restrict__ inp,
                                                        const float* __restrict__ Wg,
                                                        float* __restrict__ out, int M) {
  __shared__ float Al[64 * 128];
  __shared__ float Wl[64 * 128];
  const int t = threadIdx.x;
  const int row0 = blockIdx.x * 64;
  const float4* A4 = (const float4*)inp;
  const float4* Wg4 = (const float4*)Wg;
  float4* Al4 = (float4*)Al;
  float4* Wl4 = (float4*)Wl;

#pragma unroll
  for (int i = 0; i < 8; ++i) {
    int idx = i * 256 + t;
    int r = idx >> 5;
    float4 v = make_float4(0.f, 0.f, 0.f, 0.f);
    if (row0 + r < M) v = A4[(size_t)row0 * 32 + idx];
    Al4[idx] = v;
  }

  const int c4 = t & 31;
  const int rg = t >> 5;
  float4 acc[8];
#pragma unroll
  for (int rr = 0; rr < 8; ++rr) acc[rr] = make_float4(0.f, 0.f, 0.f, 0.f);

  for (int half = 0; half < 2; ++half) {
    __syncthreads();
#pragma unroll
    for (int i = 0; i < 8; ++i) {
      int idx = i * 256 + t;
      Wl4[idx] = Wg4[half * 2048 + idx];
    }
    __syncthreads();

#pragma unroll 4
    for (int k4 = 0; k4 < 16; ++k4) {
      float ar[8][4];
#pragma unroll
      for (int rr = 0; rr < 8; ++rr) {
        float4 a = Al4[(rg * 8 + rr) * 32 + half * 16 + k4];
        ar[rr][0] = a.x; ar[rr][1] = a.y; ar[rr][2] = a.z; ar[rr][3] = a.w;
      }
#pragma unroll
      for (int kk = 0; kk < 4; ++kk) {
        float4 w = Wl4[(k4 * 4 + kk) * 32 + c4];
#pragma unroll
        for (int rr = 0; rr < 8; ++rr) {
          acc[rr].x += ar[rr][kk] * w.x;
          acc[rr].y += ar[rr][kk] * w.y;
          acc[rr].z += ar[rr][kk] * w.z;
          acc[rr].w += ar[rr][kk] * w.w;
        }
      }
    }
  }

#pragma unroll
  for (int rr = 0; rr < 8; ++rr) {
    int r = row0 + rg * 8 + rr;
    if (r < M) {
      float4 o;
      o.x = fmaxf(acc[rr].x, 0.f);
      o.y = fmaxf(acc[rr].y, 0.f);
      o.z = fmaxf(acc[rr].z, 0.f);
      o.w = fmaxf(acc[rr].w, 0.f);
      ((float4*)out)[(size_t)r * 32 + c4] = o;
    }
  }
}

// ================= fused gather (papers): two relations + self + normalize =================
// one wave per dst row; lane holds float2 of the 128-dim vector.
__global__ __launch_bounds__(256) void gather_paper_kernel(
    const float* __restrict__ h_self, const float* __restrict__ h_w,
    const float* __restrict__ h_c, const int* __restrict__ rs_w,
    const int* __restrict__ col_w, const int* __restrict__ rs_c,
    const int* __restrict__ col_c, float* __restrict__ out, int NP) {
  int d = blockIdx.x * 4 + (threadIdx.x >> 6);
  if (d >= NP) return;
  int lane = threadIdx.x & 63;

  float2 accw = make_float2(0.f, 0.f);
  int s0 = rs_w[d], e0 = rs_w[d + 1];
  for (int j = s0; j < e0; ++j) {
    int s = col_w[j];
    float2 v = ((const float2*)(h_w + (size_t)s * 128))[lane];
    accw.x += v.x; accw.y += v.y;
  }
  float2 accc = make_float2(0.f, 0.f);
  int s1 = rs_c[d], e1 = rs_c[d + 1];
  for (int j = s1; j < e1; ++j) {
    int s = col_c[j];
    float2 v = ((const float2*)(h_c + (size_t)s * 128))[lane];
    accc.x += v.x; accc.y += v.y;
  }
  float iw = 1.f / ((float)(e0 - s0) + EPS_C);
  float ic = 1.f / ((float)(e1 - s1) + EPS_C);
  float2 hs = ((const float2*)(h_self + (size_t)d * 128))[lane];
  float2 o;
  o.x = (ALPHA_C * hs.x + accw.x * iw + accc.x * ic) * (1.f / 3.f);
  o.y = (ALPHA_C * hs.y + accw.y * iw + accc.y * ic) * (1.f / 3.f);
  ((float2*)(out + (size_t)d * 128))[lane] = o;
}

// ================= fused gather (authors): one relation + self + normalize =================
__global__ __launch_bounds__(256) void gather_author_kernel(
    const float* __restrict__ h_self, const float* __restrict__ h_b,
    const int* __restrict__ rs_b, const int* __restrict__ col_b,
    float* __restrict__ out, int NA) {
  int d = blockIdx.x * 4 + (threadIdx.x >> 6);
  if (d >= NA) return;
  int lane = threadIdx.x & 63;

  float2 acc = make_float2(0.f, 0.f);
  int s0 = rs_b[d], e0 = rs_b[d + 1];
  for (int j = s0; j < e0; ++j) {
    int s = col_b[j];
    float2 v = ((const float2*)(h_b + (size_t)s * 128))[lane];
    acc.x += v.x; acc.y += v.y;
  }
  float ib = 1.f / ((float)(e0 - s0) + EPS_C);
  float2 hs = ((const float2*)(h_self + (size_t)d * 128))[lane];
  float2 o;
  o.x = (ALPHA_C * hs.x + acc.x * ib) * 0.5f;
  o.y = (ALPHA_C * hs.y + acc.y * ib) * 0.5f;
  ((float2*)(out + (size_t)d * 128))[lane] = o;
}

// ================= final: out[M,16] = hp[M,128] @ Wout[128,16] + b =================
__global__ __launch_bounds__(256) void final_kernel(const float* __restrict__ hp,
                                                    const float* __restrict__ Wo,
                                                    const float* __restrict__ bo,
                                                    float* __restrict__ out, int M) {
  __shared__ float Wl[128 * 16];
  __shared__ float bl[16];
  int t = threadIdx.x;
#pragma unroll
  for (int i = 0; i < 8; ++i) Wl[i * 256 + t] = Wo[i * 256 + t];
  if (t < 16) bl[t] = bo[t];
  __syncthreads();

  int c4 = t & 3;
  long row = (long)blockIdx.x * 64 + (t >> 2);
  if (row >= M) return;
  const float4* a4 = (const float4*)(hp + row * 128);
  const float4* Wl4 = (const float4*)Wl;
  float4 acc = make_float4(0.f, 0.f, 0.f, 0.f);
#pragma unroll 4
  for (int k4 = 0; k4 < 32; ++k4) {
    float4 a = a4[k4];
    float av[4] = {a.x, a.y, a.z, a.w};
#pragma unroll
    for (int kk = 0; kk < 4; ++kk) {
      float4 w = Wl4[(k4 * 4 + kk) * 4 + c4];
      acc.x += av[kk] * w.x;
      acc.y += av[kk] * w.y;
      acc.z += av[kk] * w.z;
      acc.w += av[kk] * w.w;
    }
  }
  acc.x += bl[c4 * 4 + 0];
  acc.y += bl[c4 * 4 + 1];
  acc.z += bl[c4 * 4 + 2];
  acc.w += bl[c4 * 4 + 3];
  ((float4*)out)[row * 4 + c4] = acc;
}

extern "C" void kernel_launch(void* const* d_in, const int* in_sizes, int n_in,
                              void* d_out, int out_size, void* d_ws, size_t ws_size,
                              hipStream_t stream) {
  const float* x_paper = (const float*)d_in[0];
  const float* x_author = (const float*)d_in[1];
  // d_in[2] x_field: DEAD (fields never feed papers/authors; output = papers only)
  const float* Wp0 = (const float*)d_in[3];
  const float* Wp1 = (const float*)d_in[4];
  const float* Wa0 = (const float*)d_in[5];
  const float* Wa1 = (const float*)d_in[6];
  // d_in[7] W_field_0, d_in[8] W_field_1: DEAD
  const float* Wout = (const float*)d_in[9];
  const float* bout = (const float*)d_in[10];
  const int* src_w = (const int*)d_in[11];
  const int* dst_w = (const int*)d_in[12];
  const int* src_b = (const int*)d_in[13];
  const int* dst_b = (const int*)d_in[14];
  const int* src_c = (const int*)d_in[15];
  const int* dst_c = (const int*)d_in[16];
  // d_in[17]/d_in[18] topic edges: DEAD

  const int NP = in_sizes[0] / 128, NA = in_sizes[1] / 128;
  const int EW = in_sizes[11], EB = in_sizes[13], EC = in_sizes[15];

  // ---- workspace layout ----
  // feature buffers (f32): 153.6 MB
  float* hp = (float*)d_ws;               // [NP,128]
  float* ha = hp + (size_t)NP * 128;      // [NA,128]
  float* gp = ha + (size_t)NA * 128;      // [NP,128]
  float* ga = gp + (size_t)NP * 128;      // [NA,128]
  // CSR (persistent through launch): ~6.6 MB
  int* rs_w = (int*)(ga + (size_t)NA * 128);  // [NP+1]
  int* rs_c = rs_w + (NP + 1);                // [NP+1]
  int* rs_b = rs_c + (NP + 1);                // [NA+1]
  int* col_w = rs_b + (NA + 1);               // [EW]
  int* col_c = col_w + EW;                    // [EC]
  int* col_b = col_c + EC;                    // [EB]
  // transient CSR-build scratch aliased into gp/ga (done before gathers fill them)
  int* cnt_w = (int*)gp;       // [NP]
  int* cnt_c = cnt_w + NP;     // [NP]
  int* cnt_b = cnt_c + NP;     // [NA]
  int* bs_w = (int*)ga;        // [1024]
  int* bs_c = bs_w + 1024;     // [1024]
  int* bs_b = bs_c + 1024;     // [1024]

  dim3 B(256);
  auto cdiv = [](long a, long b) { return (int)((a + b - 1) / b); };
  const int nbw = cdiv(NP, 256), nbc = cdiv(NP, 256), nbb = cdiv(NA, 256);

  // ---- CSR build (graphs are layer-invariant; build once, use twice) ----
  hipMemsetAsync(cnt_w, 0, (size_t)(2 * NP + NA) * 4, stream);
  count_i_kernel<<<cdiv(EW, 256), B, 0, stream>>>(dst_w, EW, cnt_w);
  count_i_kernel<<<cdiv(EC, 256), B, 0, stream>>>(dst_c, EC, cnt_c);
  count_i_kernel<<<cdiv(EB, 256), B, 0, stream>>>(dst_b, EB, cnt_b);
  scan256_kernel<<<nbw, B, 0, stream>>>(cnt_w, NP, rs_w, bs_w);
  scan256_kernel<<<nbc, B, 0, stream>>>(cnt_c, NP, rs_c, bs_c);
  scan256_kernel<<<nbb, B, 0, stream>>>(cnt_b, NA, rs_b, bs_b);
  scan_bsums_kernel<<<1, 1024, 0, stream>>>(bs_w, nbw);
  scan_bsums_kernel<<<1, 1024, 0, stream>>>(bs_c, nbc);
  scan_bsums_kernel<<<1, 1024, 0, stream>>>(bs_b, nbb);
  add_off_kernel<<<cdiv(NP + 1, 256), B, 0, stream>>>(rs_w, NP, bs_w);
  add_off_kernel<<<cdiv(NP + 1, 256), B, 0, stream>>>(rs_c, NP, bs_c);
  add_off_kernel<<<cdiv(NA + 1, 256), B, 0, stream>>>(rs_b, NA, bs_b);
  // reuse cnt arrays as scatter cursors
  hipMemsetAsync(cnt_w, 0, (size_t)(2 * NP + NA) * 4, stream);
  scatter_kernel<<<cdiv(EW, 256), B, 0, stream>>>(src_w, dst_w, EW, rs_w, cnt_w, col_w);
  scatter_kernel<<<cdiv(EC, 256), B, 0, stream>>>(src_c, dst_c, EC, rs_c, cnt_c, col_c);
  scatter_kernel<<<cdiv(EB, 256), B, 0, stream>>>(src_b, dst_b, EB, rs_b, cnt_b, col_b);

  // ---- layer 0: h = relu(x @ W0) ----
  gemm_relu_kernel<<<cdiv(NP, 64), B, 0, stream>>>(x_paper, Wp0, hp, NP);
  gemm_relu_kernel<<<cdiv(NA, 64), B, 0, stream>>>(x_author, Wa0, ha, NA);

  // ---- layer 0 fused gather+combine: gp/ga = post-agg features ----
  gather_paper_kernel<<<cdiv(NP, 4), B, 0, stream>>>(hp, ha, hp, rs_w, col_w, rs_c, col_c,
                                                     gp, NP);
  gather_author_kernel<<<cdiv(NA, 4), B, 0, stream>>>(ha, hp, rs_b, col_b, ga, NA);

  // ---- layer 1 GEMMs (hp/ha free now; reuse as outputs) ----
  gemm_relu_kernel<<<cdiv(NP, 64), B, 0, stream>>>(gp, Wp1, hp, NP);
  gemm_relu_kernel<<<cdiv(NA, 64), B, 0, stream>>>(ga, Wa1, ha, NA);

  // ---- layer 1 fused gather (papers only; author/field outputs are dead) ----
  gather_paper_kernel<<<cdiv(NP, 4), B, 0, stream>>>(hp, ha, hp, rs_w, col_w, rs_c, col_c,
                                                     gp, NP);

  // ---- final: out = gp @ W_out + b_out ----
  final_kernel<<<cdiv(NP, 64), B, 0, stream>>>(gp, Wout, bout, (float*)d_out, NP);
}

// Round 6
// 655.000 us; speedup vs baseline: 3.7254x; 1.1963x over previous
//
#include <hip/hip_runtime.h>

#define ALPHA_C 0.1f
#define EPS_C 1e-4f

__device__ __forceinline__ float b2f(ushort u) {
  return __uint_as_float(((unsigned int)u) << 16);
}
__device__ __forceinline__ ushort f2b(float f) {
  unsigned int u = __float_as_uint(f);
  u += 0x7fffu + ((u >> 16) & 1u);
  return (ushort)(u >> 16);
}
// unpack packed 2xbf16 (little-endian: low ushort = even dim)
__device__ __forceinline__ float2 up2(unsigned int u) {
  return make_float2(b2f((ushort)(u & 0xffffu)), b2f((ushort)(u >> 16)));
}

// ================= CSR build =================

__global__ __launch_bounds__(256) void count_i_kernel(const int* __restrict__ dst, int E,
                                                      int* __restrict__ cnt) {
  int i = blockIdx.x * 256 + threadIdx.x;
  if (i < E) atomicAdd(&cnt[dst[i]], 1);
}

__global__ __launch_bounds__(256) void scan256_kernel(const int* __restrict__ cnt, int n,
                                                      int* __restrict__ rs,
                                                      int* __restrict__ bsum) {
  __shared__ int sm[256];
  int t = threadIdx.x;
  int i = blockIdx.x * 256 + t;
  int v = (i < n) ? cnt[i] : 0;
  sm[t] = v;
  __syncthreads();
  int acc = v;
  for (int off = 1; off < 256; off <<= 1) {
    int add = (t >= off) ? sm[t - off] : 0;
    __syncthreads();
    acc += add;
    sm[t] = acc;
    __syncthreads();
  }
  if (i < n) rs[i] = acc - v;
  if (i == n - 1) rs[n] = acc;
  if (t == 255) bsum[blockIdx.x] = acc;
}

__global__ __launch_bounds__(1024) void scan_bsums_kernel(int* __restrict__ bsum, int nb) {
  __shared__ int sm[1024];
  int t = threadIdx.x;
  int v = (t < nb) ? bsum[t] : 0;
  sm[t] = v;
  __syncthreads();
  int acc = v;
  for (int off = 1; off < 1024; off <<= 1) {
    int add = (t >= off) ? sm[t - off] : 0;
    __syncthreads();
    acc += add;
    sm[t] = acc;
    __syncthreads();
  }
  if (t < nb) bsum[t] = acc - v;
}

__global__ __launch_bounds__(256) void add_off_kernel(int* __restrict__ rs, int n,
                                                      const int* __restrict__ bsum) {
  int i = blockIdx.x * 256 + threadIdx.x;
  if (i <= n) {
    int b = ((i == n) ? (n - 1) : i) >> 8;
    rs[i] += bsum[b];
  }
}

__global__ __launch_bounds__(256) void scatter_kernel(const int* __restrict__ src,
                                                      const int* __restrict__ dst, int E,
                                                      const int* __restrict__ rs,
                                                      int* __restrict__ cur,
                                                      int* __restrict__ col) {
  int i = blockIdx.x * 256 + threadIdx.x;
  if (i < E) {
    int d = dst[i];
    int pos = atomicAdd(&cur[d], 1);
    col[rs[d] + pos] = src[i];
  }
}

// ================= GEMM + ReLU -> bf16: out[M,128] = relu(in[M,128] @ W[128,128]) ==========
// in f32, W f32, out bf16 (consumed only by gathers). 256 thr, 64 rows/block, 64KB LDS.
__global__ __launch_bounds__(256) void gemm_relu_kernel(const float* __restrict__ inp,
                                                        const float* __restrict__ Wg,
                                                        ushort* __restrict__ out, int M) {
  __shared__ float Al[64 * 128];
  __shared__ float Wl[64 * 128];
  const int t = threadIdx.x;
  const int row0 = blockIdx.x * 64;
  const float4* A4 = (const float4*)inp;
  const float4* Wg4 = (const float4*)Wg;
  float4* Al4 = (float4*)Al;
  float4* Wl4 = (float4*)Wl;

#pragma unroll
  for (int i = 0; i < 8; ++i) {
    int idx = i * 256 + t;
    int r = idx >> 5;
    float4 v = make_float4(0.f, 0.f, 0.f, 0.f);
    if (row0 + r < M) v = A4[(size_t)row0 * 32 + idx];
    Al4[idx] = v;
  }

  const int c4 = t & 31;
  const int rg = t >> 5;
  float4 acc[8];
#pragma unroll
  for (int rr = 0; rr < 8; ++rr) acc[rr] = make_float4(0.f, 0.f, 0.f, 0.f);

  for (int half = 0; half < 2; ++half) {
    __syncthreads();
#pragma unroll
    for (int i = 0; i < 8; ++i) {
      int idx = i * 256 + t;
      Wl4[idx] = Wg4[half * 2048 + idx];
    }
    __syncthreads();

#pragma unroll 4
    for (int k4 = 0; k4 < 16; ++k4) {
      float ar[8][4];
#pragma unroll
      for (int rr = 0; rr < 8; ++rr) {
        float4 a = Al4[(rg * 8 + rr) * 32 + half * 16 + k4];
        ar[rr][0] = a.x; ar[rr][1] = a.y; ar[rr][2] = a.z; ar[rr][3] = a.w;
      }
#pragma unroll
      for (int kk = 0; kk < 4; ++kk) {
        float4 w = Wl4[(k4 * 4 + kk) * 32 + c4];
#pragma unroll
        for (int rr = 0; rr < 8; ++rr) {
          acc[rr].x += ar[rr][kk] * w.x;
          acc[rr].y += ar[rr][kk] * w.y;
          acc[rr].z += ar[rr][kk] * w.z;
          acc[rr].w += ar[rr][kk] * w.w;
        }
      }
    }
  }

#pragma unroll
  for (int rr = 0; rr < 8; ++rr) {
    int r = row0 + rg * 8 + rr;
    if (r < M) {
      ushort4 o;
      o.x = f2b(fmaxf(acc[rr].x, 0.f));
      o.y = f2b(fmaxf(acc[rr].y, 0.f));
      o.z = f2b(fmaxf(acc[rr].z, 0.f));
      o.w = f2b(fmaxf(acc[rr].w, 0.f));
      ((ushort4*)out)[(size_t)r * 32 + c4] = o;  // 128 bf16 = 32 ushort4 per row
    }
  }
}

// ================= fused gather (papers), bf16 in / f32 out =================
// one wave per dst row; lane holds dims [2*lane, 2*lane+1] (one packed uint per row).
// 4-wide unrolled neighbor loop: 4 independent index loads, then 4 independent row loads.
__global__ __launch_bounds__(256) void gather_paper_kernel(
    const ushort* __restrict__ hbp, const ushort* __restrict__ hba,
    const int* __restrict__ rs_w, const int* __restrict__ col_w,
    const int* __restrict__ rs_c, const int* __restrict__ col_c,
    float* __restrict__ out, int NP) {
  int d = blockIdx.x * 4 + (threadIdx.x >> 6);
  if (d >= NP) return;
  int lane = threadIdx.x & 63;
  const unsigned int* hw = (const unsigned int*)hba;  // row stride 64 uints
  const unsigned int* hc = (const unsigned int*)hbp;

  float2 accw = make_float2(0.f, 0.f);
  int s0 = rs_w[d], e0 = rs_w[d + 1];
  int j = s0;
  for (; j + 4 <= e0; j += 4) {
    int i0 = col_w[j], i1 = col_w[j + 1], i2 = col_w[j + 2], i3 = col_w[j + 3];
    unsigned int u0 = hw[(size_t)i0 * 64 + lane];
    unsigned int u1 = hw[(size_t)i1 * 64 + lane];
    unsigned int u2 = hw[(size_t)i2 * 64 + lane];
    unsigned int u3 = hw[(size_t)i3 * 64 + lane];
    float2 v0 = up2(u0), v1 = up2(u1), v2 = up2(u2), v3 = up2(u3);
    accw.x += (v0.x + v1.x) + (v2.x + v3.x);
    accw.y += (v0.y + v1.y) + (v2.y + v3.y);
  }
  for (; j < e0; ++j) {
    float2 v = up2(hw[(size_t)col_w[j] * 64 + lane]);
    accw.x += v.x; accw.y += v.y;
  }

  float2 accc = make_float2(0.f, 0.f);
  int s1 = rs_c[d], e1 = rs_c[d + 1];
  j = s1;
  for (; j + 4 <= e1; j += 4) {
    int i0 = col_c[j], i1 = col_c[j + 1], i2 = col_c[j + 2], i3 = col_c[j + 3];
    unsigned int u0 = hc[(size_t)i0 * 64 + lane];
    unsigned int u1 = hc[(size_t)i1 * 64 + lane];
    unsigned int u2 = hc[(size_t)i2 * 64 + lane];
    unsigned int u3 = hc[(size_t)i3 * 64 + lane];
    float2 v0 = up2(u0), v1 = up2(u1), v2 = up2(u2), v3 = up2(u3);
    accc.x += (v0.x + v1.x) + (v2.x + v3.x);
    accc.y += (v0.y + v1.y) + (v2.y + v3.y);
  }
  for (; j < e1; ++j) {
    float2 v = up2(hc[(size_t)col_c[j] * 64 + lane]);
    accc.x += v.x; accc.y += v.y;
  }

  float iw = 1.f / ((float)(e0 - s0) + EPS_C);
  float ic = 1.f / ((float)(e1 - s1) + EPS_C);
  float2 hs = up2(hc[(size_t)d * 64 + lane]);
  float2 o;
  o.x = (ALPHA_C * hs.x + accw.x * iw + accc.x * ic) * (1.f / 3.f);
  o.y = (ALPHA_C * hs.y + accw.y * iw + accc.y * ic) * (1.f / 3.f);
  ((float2*)(out + (size_t)d * 128))[lane] = o;
}

// ================= fused gather (authors), bf16 in / f32 out =================
__global__ __launch_bounds__(256) void gather_author_kernel(
    const ushort* __restrict__ hba, const ushort* __restrict__ hbp,
    const int* __restrict__ rs_b, const int* __restrict__ col_b,
    float* __restrict__ out, int NA) {
  int d = blockIdx.x * 4 + (threadIdx.x >> 6);
  if (d >= NA) return;
  int lane = threadIdx.x & 63;
  const unsigned int* hb = (const unsigned int*)hbp;
  const unsigned int* hs_ = (const unsigned int*)hba;

  float2 acc = make_float2(0.f, 0.f);
  int s0 = rs_b[d], e0 = rs_b[d + 1];
  int j = s0;
  for (; j + 4 <= e0; j += 4) {
    int i0 = col_b[j], i1 = col_b[j + 1], i2 = col_b[j + 2], i3 = col_b[j + 3];
    unsigned int u0 = hb[(size_t)i0 * 64 + lane];
    unsigned int u1 = hb[(size_t)i1 * 64 + lane];
    unsigned int u2 = hb[(size_t)i2 * 64 + lane];
    unsigned int u3 = hb[(size_t)i3 * 64 + lane];
    float2 v0 = up2(u0), v1 = up2(u1), v2 = up2(u2), v3 = up2(u3);
    acc.x += (v0.x + v1.x) + (v2.x + v3.x);
    acc.y += (v0.y + v1.y) + (v2.y + v3.y);
  }
  for (; j < e0; ++j) {
    float2 v = up2(hb[(size_t)col_b[j] * 64 + lane]);
    acc.x += v.x; acc.y += v.y;
  }

  float ib = 1.f / ((float)(e0 - s0) + EPS_C);
  float2 hs = up2(hs_[(size_t)d * 64 + lane]);
  float2 o;
  o.x = (ALPHA_C * hs.x + acc.x * ib) * 0.5f;
  o.y = (ALPHA_C * hs.y + acc.y * ib) * 0.5f;
  ((float2*)(out + (size_t)d * 128))[lane] = o;
}

// ================= final: out[M,16] = hp[M,128] @ Wout[128,16] + b (all f32) ==============
__global__ __launch_bounds__(256) void final_kernel(const float* __restrict__ hp,
                                                    const float* __restrict__ Wo,
                                                    const float* __restrict__ bo,
                                                    float* __restrict__ out, int M) {
  __shared__ float Wl[128 * 16];
  __shared__ float bl[16];
  int t = threadIdx.x;
#pragma unroll
  for (int i = 0; i < 8; ++i) Wl[i * 256 + t] = Wo[i * 256 + t];
  if (t < 16) bl[t] = bo[t];
  __syncthreads();

  int c4 = t & 3;
  long row = (long)blockIdx.x * 64 + (t >> 2);
  if (row >= M) return;
  const float4* a4 = (const float4*)(hp + row * 128);
  const float4* Wl4 = (const float4*)Wl;
  float4 acc = make_float4(0.f, 0.f, 0.f, 0.f);
#pragma unroll 4
  for (int k4 = 0; k4 < 32; ++k4) {
    float4 a = a4[k4];
    float av[4] = {a.x, a.y, a.z, a.w};
#pragma unroll
    for (int kk = 0; kk < 4; ++kk) {
      float4 w = Wl4[(k4 * 4 + kk) * 4 + c4];
      acc.x += av[kk] * w.x;
      acc.y += av[kk] * w.y;
      acc.z += av[kk] * w.z;
      acc.w += av[kk] * w.w;
    }
  }
  acc.x += bl[c4 * 4 + 0];
  acc.y += bl[c4 * 4 + 1];
  acc.z += bl[c4 * 4 + 2];
  acc.w += bl[c4 * 4 + 3];
  ((float4*)out)[row * 4 + c4] = acc;
}

extern "C" void kernel_launch(void* const* d_in, const int* in_sizes, int n_in,
                              void* d_out, int out_size, void* d_ws, size_t ws_size,
                              hipStream_t stream) {
  const float* x_paper = (const float*)d_in[0];
  const float* x_author = (const float*)d_in[1];
  // d_in[2] x_field: DEAD (fields never feed papers/authors; output = papers only)
  const float* Wp0 = (const float*)d_in[3];
  const float* Wp1 = (const float*)d_in[4];
  const float* Wa0 = (const float*)d_in[5];
  const float* Wa1 = (const float*)d_in[6];
  // d_in[7] W_field_0, d_in[8] W_field_1: DEAD
  const float* Wout = (const float*)d_in[9];
  const float* bout = (const float*)d_in[10];
  const int* src_w = (const int*)d_in[11];
  const int* dst_w = (const int*)d_in[12];
  const int* src_b = (const int*)d_in[13];
  const int* dst_b = (const int*)d_in[14];
  const int* src_c = (const int*)d_in[15];
  const int* dst_c = (const int*)d_in[16];
  // d_in[17]/d_in[18] topic edges: DEAD

  const int NP = in_sizes[0] / 128, NA = in_sizes[1] / 128;
  const int EW = in_sizes[11], EB = in_sizes[13], EC = in_sizes[15];

  // ---- workspace layout (~122 MB) ----
  float* gp = (float*)d_ws;                     // [NP,128] f32 gather out (papers)
  float* ga = gp + (size_t)NP * 128;            // [NA,128] f32 gather out (authors)
  ushort* hbp = (ushort*)(ga + (size_t)NA * 128);  // [NP,128] bf16 h (papers)
  ushort* hba = hbp + (size_t)NP * 128;            // [NA,128] bf16 h (authors)
  int* rs_w = (int*)(hba + (size_t)NA * 128);   // [NP+1]
  int* rs_c = rs_w + (NP + 1);                  // [NP+1]
  int* rs_b = rs_c + (NP + 1);                  // [NA+1]
  int* col_w = rs_b + (NA + 1);                 // [EW]
  int* col_c = col_w + EW;                      // [EC]
  int* col_b = col_c + EC;                      // [EB]
  // transient CSR-build scratch aliased into gp/ga (CSR build finishes before gathers)
  int* cnt_w = (int*)gp;       // [NP]
  int* cnt_c = cnt_w + NP;     // [NP]
  int* cnt_b = cnt_c + NP;     // [NA]
  int* bs_w = (int*)ga;        // [1024]
  int* bs_c = bs_w + 1024;     // [1024]
  int* bs_b = bs_c + 1024;     // [1024]

  dim3 B(256);
  auto cdiv = [](long a, long b) { return (int)((a + b - 1) / b); };
  const int nbw = cdiv(NP, 256), nbc = cdiv(NP, 256), nbb = cdiv(NA, 256);

  // ---- CSR build (graphs are layer-invariant; build once, use twice) ----
  hipMemsetAsync(cnt_w, 0, (size_t)(2 * NP + NA) * 4, stream);
  count_i_kernel<<<cdiv(EW, 256), B, 0, stream>>>(dst_w, EW, cnt_w);
  count_i_kernel<<<cdiv(EC, 256), B, 0, stream>>>(dst_c, EC, cnt_c);
  count_i_kernel<<<cdiv(EB, 256), B, 0, stream>>>(dst_b, EB, cnt_b);
  scan256_kernel<<<nbw, B, 0, stream>>>(cnt_w, NP, rs_w, bs_w);
  scan256_kernel<<<nbc, B, 0, stream>>>(cnt_c, NP, rs_c, bs_c);
  scan256_kernel<<<nbb, B, 0, stream>>>(cnt_b, NA, rs_b, bs_b);
  scan_bsums_kernel<<<1, 1024, 0, stream>>>(bs_w, nbw);
  scan_bsums_kernel<<<1, 1024, 0, stream>>>(bs_c, nbc);
  scan_bsums_kernel<<<1, 1024, 0, stream>>>(bs_b, nbb);
  add_off_kernel<<<cdiv(NP + 1, 256), B, 0, stream>>>(rs_w, NP, bs_w);
  add_off_kernel<<<cdiv(NP + 1, 256), B, 0, stream>>>(rs_c, NP, bs_c);
  add_off_kernel<<<cdiv(NA + 1, 256), B, 0, stream>>>(rs_b, NA, bs_b);
  hipMemsetAsync(cnt_w, 0, (size_t)(2 * NP + NA) * 4, stream);
  scatter_kernel<<<cdiv(EW, 256), B, 0, stream>>>(src_w, dst_w, EW, rs_w, cnt_w, col_w);
  scatter_kernel<<<cdiv(EC, 256), B, 0, stream>>>(src_c, dst_c, EC, rs_c, cnt_c, col_c);
  scatter_kernel<<<cdiv(EB, 256), B, 0, stream>>>(src_b, dst_b, EB, rs_b, cnt_b, col_b);

  // ---- layer 0: h = relu(x @ W0) -> bf16 ----
  gemm_relu_kernel<<<cdiv(NP, 64), B, 0, stream>>>(x_paper, Wp0, hbp, NP);
  gemm_relu_kernel<<<cdiv(NA, 64), B, 0, stream>>>(x_author, Wa0, hba, NA);

  // ---- layer 0 fused gather+combine (bf16 in, f32 out) ----
  gather_paper_kernel<<<cdiv(NP, 4), B, 0, stream>>>(hbp, hba, rs_w, col_w, rs_c, col_c,
                                                     gp, NP);
  gather_author_kernel<<<cdiv(NA, 4), B, 0, stream>>>(hba, hbp, rs_b, col_b, ga, NA);

  // ---- layer 1 GEMMs (read f32 gather outputs, write bf16 h) ----
  gemm_relu_kernel<<<cdiv(NP, 64), B, 0, stream>>>(gp, Wp1, hbp, NP);
  gemm_relu_kernel<<<cdiv(NA, 64), B, 0, stream>>>(ga, Wa1, hba, NA);

  // ---- layer 1 fused gather (papers only; author/field outputs are dead) ----
  gather_paper_kernel<<<cdiv(NP, 4), B, 0, stream>>>(hbp, hba, rs_w, col_w, rs_c, col_c,
                                                     gp, NP);

  // ---- final: out = gp @ W_out + b_out ----
  final_kernel<<<cdiv(NP, 64), B, 0, stream>>>(gp, Wout, bout, (float*)d_out, NP);
}

// Round 7
// 507.017 us; speedup vs baseline: 4.8127x; 1.2919x over previous
//
#include <hip/hip_runtime.h>

#define ALPHA_C 0.1f
#define EPS_C 1e-4f

typedef __attribute__((ext_vector_type(8))) short short8v;   // 8 bf16 (4 VGPR)
typedef __attribute__((ext_vector_type(4))) float f32x4;     // MFMA acc

__device__ __forceinline__ float b2f(ushort u) {
  return __uint_as_float(((unsigned int)u) << 16);
}
__device__ __forceinline__ ushort f2b(float f) {
  unsigned int u = __float_as_uint(f);
  u += 0x7fffu + ((u >> 16) & 1u);
  return (ushort)(u >> 16);
}
__device__ __forceinline__ float2 up2(unsigned int u) {
  return make_float2(b2f((ushort)(u & 0xffffu)), b2f((ushort)(u >> 16)));
}

// ================= CSR build (merged 3-relation kernels) =================

__global__ __launch_bounds__(256) void count3_kernel(
    const int* __restrict__ d0, int E0, int* __restrict__ c0,
    const int* __restrict__ d1, int E1, int* __restrict__ c1,
    const int* __restrict__ d2, int E2, int* __restrict__ c2) {
  int i = blockIdx.x * 256 + threadIdx.x;
  if (i < E0) atomicAdd(&c0[d0[i]], 1);
  else if (i < E0 + E1) atomicAdd(&c1[d1[i - E0]], 1);
  else if (i < E0 + E1 + E2) atomicAdd(&c2[d2[i - E0 - E1]], 1);
}

__global__ __launch_bounds__(256) void scan3_kernel(
    const int* __restrict__ c0, int n0, int* __restrict__ r0, int* __restrict__ b0,
    const int* __restrict__ c1, int n1, int* __restrict__ r1, int* __restrict__ b1,
    const int* __restrict__ c2, int n2, int* __restrict__ r2, int* __restrict__ b2,
    int nb0, int nb1) {
  __shared__ int sm[256];
  int blk = blockIdx.x;
  const int* cnt; int n; int* rs; int* bsum; int lb;
  if (blk < nb0)            { cnt = c0; n = n0; rs = r0; bsum = b0; lb = blk; }
  else if (blk < nb0 + nb1) { cnt = c1; n = n1; rs = r1; bsum = b1; lb = blk - nb0; }
  else                      { cnt = c2; n = n2; rs = r2; bsum = b2; lb = blk - nb0 - nb1; }
  int t = threadIdx.x;
  int i = lb * 256 + t;
  int v = (i < n) ? cnt[i] : 0;
  sm[t] = v;
  __syncthreads();
  int acc = v;
  for (int off = 1; off < 256; off <<= 1) {
    int add = (t >= off) ? sm[t - off] : 0;
    __syncthreads();
    acc += add;
    sm[t] = acc;
    __syncthreads();
  }
  if (i < n) rs[i] = acc - v;
  if (i == n - 1) rs[n] = acc;
  if (t == 255) bsum[lb] = acc;
}

// grid=3 blocks of 1024; block b scans its own bsum array (nb <= 1024)
__global__ __launch_bounds__(1024) void bsum3_kernel(int* __restrict__ b0, int nb0,
                                                     int* __restrict__ b1, int nb1,
                                                     int* __restrict__ b2, int nb2) {
  __shared__ int sm[1024];
  int* bsum; int nb;
  if (blockIdx.x == 0)      { bsum = b0; nb = nb0; }
  else if (blockIdx.x == 1) { bsum = b1; nb = nb1; }
  else                      { bsum = b2; nb = nb2; }
  int t = threadIdx.x;
  int v = (t < nb) ? bsum[t] : 0;
  sm[t] = v;
  __syncthreads();
  int acc = v;
  for (int off = 1; off < 1024; off <<= 1) {
    int add = (t >= off) ? sm[t - off] : 0;
    __syncthreads();
    acc += add;
    sm[t] = acc;
    __syncthreads();
  }
  if (t < nb) bsum[t] = acc - v;
}

__global__ __launch_bounds__(256) void addoff3_kernel(
    int* __restrict__ r0, int n0, const int* __restrict__ b0,
    int* __restrict__ r1, int n1, const int* __restrict__ b1,
    int* __restrict__ r2, int n2, const int* __restrict__ b2) {
  int i = blockIdx.x * 256 + threadIdx.x;
  int* rs; const int* bsum; int n; int li = i;
  if (li <= n0) { rs = r0; bsum = b0; n = n0; }
  else {
    li -= n0 + 1;
    if (li <= n1) { rs = r1; bsum = b1; n = n1; }
    else { li -= n1 + 1; if (li > n2) return; rs = r2; bsum = b2; n = n2; }
  }
  int b = ((li == n) ? (n - 1) : li) >> 8;
  rs[li] += bsum[b];
}

__global__ __launch_bounds__(256) void scatter3_kernel(
    const int* __restrict__ s0, const int* __restrict__ d0, int E0,
    const int* __restrict__ rs0, int* __restrict__ cu0, int* __restrict__ co0,
    const int* __restrict__ s1, const int* __restrict__ d1, int E1,
    const int* __restrict__ rs1, int* __restrict__ cu1, int* __restrict__ co1,
    const int* __restrict__ s2, const int* __restrict__ d2, int E2,
    const int* __restrict__ rs2, int* __restrict__ cu2, int* __restrict__ co2) {
  int i = blockIdx.x * 256 + threadIdx.x;
  const int *src, *dst, *rs; int* cur; int* col; int li = i;
  if (li < E0) { src = s0; dst = d0; rs = rs0; cur = cu0; col = co0; }
  else {
    li -= E0;
    if (li < E1) { src = s1; dst = d1; rs = rs1; cur = cu1; col = co1; }
    else { li -= E1; if (li >= E2) return; src = s2; dst = d2; rs = rs2; cur = cu2; col = co2; }
  }
  int d = dst[li];
  int pos = atomicAdd(&cur[d], 1);
  col[rs[d] + pos] = src[li];
}

// ================= weight prep: Wt[c][k] = bf16(W[k][c]), 4 matrices =================
__global__ __launch_bounds__(256) void prep_w_kernel(
    const float* __restrict__ W0, const float* __restrict__ W1,
    const float* __restrict__ W2, const float* __restrict__ W3,
    ushort* __restrict__ o0, ushort* __restrict__ o1,
    ushort* __restrict__ o2, ushort* __restrict__ o3) {
  const float* W; ushort* o;
  switch (blockIdx.y) {
    case 0: W = W0; o = o0; break;
    case 1: W = W1; o = o1; break;
    case 2: W = W2; o = o2; break;
    default: W = W3; o = o3; break;
  }
  int idx = blockIdx.x * 256 + threadIdx.x;  // grid.x = 64 → 16384 elems
  int k = idx >> 7, c = idx & 127;
  o[c * 128 + k] = f2b(W[idx]);
}

// ================= MFMA GEMM + ReLU -> bf16 =================
// Two independent GEMMs (paper/author) in one dispatch, segmented grid.
// out[M,128] = relu(in[M,128] @ W), in f32, Wt bf16 [c][k] pre-transposed, out bf16.
// Block: 256 thr = 4 waves, 64 rows. LDS: A 16KB + Wt 32KB = 48KB (XOR-swizzled).
// mfma_f32_16x16x32_bf16 layouts (verified m89): A row=lane&15,k=(lane>>4)*8+i;
// B col=lane&15,k=(lane>>4)*8+i; C/D col=lane&15,row=(lane>>4)*4+reg.
__global__ __launch_bounds__(256) void gemm_mfma_kernel(
    const float* __restrict__ inA, const ushort* __restrict__ WtA,
    ushort* __restrict__ outA, int MA,
    const float* __restrict__ inB, const ushort* __restrict__ WtB,
    ushort* __restrict__ outB, int MB) {
  __shared__ ushort Asw[64 * 128];
  __shared__ ushort Wsw[128 * 128];
  const int nblkA = (MA + 63) >> 6;
  const float* inp; const ushort* Wt; ushort* out; int M; int row0;
  if ((int)blockIdx.x < nblkA) {
    inp = inA; Wt = WtA; out = outA; M = MA; row0 = blockIdx.x * 64;
  } else {
    inp = inB; Wt = WtB; out = outB; M = MB; row0 = (blockIdx.x - nblkA) * 64;
  }
  const int t = threadIdx.x;

  {  // stage Wt: 16384 ushort = 4096 ushort4, linear global -> swizzled LDS
    const ushort4* Wg4 = (const ushort4*)Wt;
#pragma unroll
    for (int i = 0; i < 16; ++i) {
      int idx4 = i * 256 + t;
      int us = idx4 * 4;
      int row = us >> 7;                       // Wt row = output col c
      int sw = us ^ ((row & 7) << 3);          // toggle byte bits 4..6
      *(ushort4*)&Wsw[sw] = Wg4[idx4];
    }
  }
  {  // stage A: f32 -> bf16, swizzled
    const float4* A4 = (const float4*)inp;
#pragma unroll
    for (int i = 0; i < 8; ++i) {
      int idx4 = i * 256 + t;                  // float4 idx; 32 per row
      int row = idx4 >> 5;
      float4 v = make_float4(0.f, 0.f, 0.f, 0.f);
      if (row0 + row < M) v = A4[(size_t)row0 * 32 + idx4];
      ushort4 b;
      b.x = f2b(v.x); b.y = f2b(v.y); b.z = f2b(v.z); b.w = f2b(v.w);
      int us = idx4 * 4;
      int sw = us ^ ((row & 7) << 3);
      *(ushort4*)&Asw[sw] = b;
    }
  }
  __syncthreads();

  const int w = t >> 6;    // wave id: rows w*16..w*16+15
  const int l = t & 63;
  const int lr = l & 15;   // A-row / B-col within 16
  const int kg = l >> 4;   // k-group: k offset kg*8

  short8v a[4];
#pragma unroll
  for (int ks = 0; ks < 4; ++ks) {
    int row = w * 16 + lr;
    int us = row * 128 + ks * 32 + kg * 8;
    int sw = us ^ ((row & 7) << 3);
    a[ks] = *(const short8v*)&Asw[sw];
  }
  f32x4 acc[8];
#pragma unroll
  for (int n = 0; n < 8; ++n) acc[n] = (f32x4){0.f, 0.f, 0.f, 0.f};
#pragma unroll
  for (int n = 0; n < 8; ++n) {
    int c = n * 16 + lr;
#pragma unroll
    for (int ks = 0; ks < 4; ++ks) {
      int us = c * 128 + ks * 32 + kg * 8;
      int sw = us ^ ((c & 7) << 3);
      short8v b = *(const short8v*)&Wsw[sw];
      acc[n] = __builtin_amdgcn_mfma_f32_16x16x32_bf16(a[ks], b, acc[n], 0, 0, 0);
    }
  }
  // epilogue: relu -> bf16. lane writes col n*16+lr, rows w*16 + kg*4 + r.
#pragma unroll
  for (int n = 0; n < 8; ++n) {
#pragma unroll
    for (int r = 0; r < 4; ++r) {
      int row = row0 + w * 16 + kg * 4 + r;
      if (row < M) out[(size_t)row * 128 + n * 16 + lr] = f2b(fmaxf(acc[n][r], 0.f));
    }
  }
}

// ================= fused gather (papers), bf16 in / f32 out =================
__global__ __launch_bounds__(256) void gather_paper_kernel(
    const ushort* __restrict__ hbp, const ushort* __restrict__ hba,
    const int* __restrict__ rs_w, const int* __restrict__ col_w,
    const int* __restrict__ rs_c, const int* __restrict__ col_c,
    float* __restrict__ out, int NP) {
  int d = blockIdx.x * 4 + (threadIdx.x >> 6);
  if (d >= NP) return;
  int lane = threadIdx.x & 63;
  const unsigned int* hw = (const unsigned int*)hba;
  const unsigned int* hc = (const unsigned int*)hbp;

  float2 accw = make_float2(0.f, 0.f);
  int s0 = rs_w[d], e0 = rs_w[d + 1];
  int j = s0;
  for (; j + 4 <= e0; j += 4) {
    int i0 = col_w[j], i1 = col_w[j + 1], i2 = col_w[j + 2], i3 = col_w[j + 3];
    unsigned int u0 = hw[(size_t)i0 * 64 + lane];
    unsigned int u1 = hw[(size_t)i1 * 64 + lane];
    unsigned int u2 = hw[(size_t)i2 * 64 + lane];
    unsigned int u3 = hw[(size_t)i3 * 64 + lane];
    float2 v0 = up2(u0), v1 = up2(u1), v2 = up2(u2), v3 = up2(u3);
    accw.x += (v0.x + v1.x) + (v2.x + v3.x);
    accw.y += (v0.y + v1.y) + (v2.y + v3.y);
  }
  for (; j < e0; ++j) {
    float2 v = up2(hw[(size_t)col_w[j] * 64 + lane]);
    accw.x += v.x; accw.y += v.y;
  }

  float2 accc = make_float2(0.f, 0.f);
  int s1 = rs_c[d], e1 = rs_c[d + 1];
  j = s1;
  for (; j + 4 <= e1; j += 4) {
    int i0 = col_c[j], i1 = col_c[j + 1], i2 = col_c[j + 2], i3 = col_c[j + 3];
    unsigned int u0 = hc[(size_t)i0 * 64 + lane];
    unsigned int u1 = hc[(size_t)i1 * 64 + lane];
    unsigned int u2 = hc[(size_t)i2 * 64 + lane];
    unsigned int u3 = hc[(size_t)i3 * 64 + lane];
    float2 v0 = up2(u0), v1 = up2(u1), v2 = up2(u2), v3 = up2(u3);
    accc.x += (v0.x + v1.x) + (v2.x + v3.x);
    accc.y += (v0.y + v1.y) + (v2.y + v3.y);
  }
  for (; j < e1; ++j) {
    float2 v = up2(hc[(size_t)col_c[j] * 64 + lane]);
    accc.x += v.x; accc.y += v.y;
  }

  float iw = 1.f / ((float)(e0 - s0) + EPS_C);
  float ic = 1.f / ((float)(e1 - s1) + EPS_C);
  float2 hs = up2(hc[(size_t)d * 64 + lane]);
  float2 o;
  o.x = (ALPHA_C * hs.x + accw.x * iw + accc.x * ic) * (1.f / 3.f);
  o.y = (ALPHA_C * hs.y + accw.y * iw + accc.y * ic) * (1.f / 3.f);
  ((float2*)(out + (size_t)d * 128))[lane] = o;
}

// ================= fused gather (authors), bf16 in / f32 out =================
__global__ __launch_bounds__(256) void gather_author_kernel(
    const ushort* __restrict__ hba, const ushort* __restrict__ hbp,
    const int* __restrict__ rs_b, const int* __restrict__ col_b,
    float* __restrict__ out, int NA) {
  int d = blockIdx.x * 4 + (threadIdx.x >> 6);
  if (d >= NA) return;
  int lane = threadIdx.x & 63;
  const unsigned int* hb = (const unsigned int*)hbp;
  const unsigned int* hs_ = (const unsigned int*)hba;

  float2 acc = make_float2(0.f, 0.f);
  int s0 = rs_b[d], e0 = rs_b[d + 1];
  int j = s0;
  for (; j + 4 <= e0; j += 4) {
    int i0 = col_b[j], i1 = col_b[j + 1], i2 = col_b[j + 2], i3 = col_b[j + 3];
    unsigned int u0 = hb[(size_t)i0 * 64 + lane];
    unsigned int u1 = hb[(size_t)i1 * 64 + lane];
    unsigned int u2 = hb[(size_t)i2 * 64 + lane];
    unsigned int u3 = hb[(size_t)i3 * 64 + lane];
    float2 v0 = up2(u0), v1 = up2(u1), v2 = up2(u2), v3 = up2(u3);
    acc.x += (v0.x + v1.x) + (v2.x + v3.x);
    acc.y += (v0.y + v1.y) + (v2.y + v3.y);
  }
  for (; j < e0; ++j) {
    float2 v = up2(hb[(size_t)col_b[j] * 64 + lane]);
    acc.x += v.x; acc.y += v.y;
  }

  float ib = 1.f / ((float)(e0 - s0) + EPS_C);
  float2 hs = up2(hs_[(size_t)d * 64 + lane]);
  float2 o;
  o.x = (ALPHA_C * hs.x + acc.x * ib) * 0.5f;
  o.y = (ALPHA_C * hs.y + acc.y * ib) * 0.5f;
  ((float2*)(out + (size_t)d * 128))[lane] = o;
}

// ================= final: out[M,16] = hp[M,128] @ Wout[128,16] + b (all f32) ==============
__global__ __launch_bounds__(256) void final_kernel(const float* __restrict__ hp,
                                                    const float* __restrict__ Wo,
                                                    const float* __restrict__ bo,
                                                    float* __restrict__ out, int M) {
  __shared__ float Wl[128 * 16];
  __shared__ float bl[16];
  int t = threadIdx.x;
#pragma unroll
  for (int i = 0; i < 8; ++i) Wl[i * 256 + t] = Wo[i * 256 + t];
  if (t < 16) bl[t] = bo[t];
  __syncthreads();

  int c4 = t & 3;
  long row = (long)blockIdx.x * 64 + (t >> 2);
  if (row >= M) return;
  const float4* a4 = (const float4*)(hp + row * 128);
  const float4* Wl4 = (const float4*)Wl;
  float4 acc = make_float4(0.f, 0.f, 0.f, 0.f);
#pragma unroll 4
  for (int k4 = 0; k4 < 32; ++k4) {
    float4 a = a4[k4];
    float av[4] = {a.x, a.y, a.z, a.w};
#pragma unroll
    for (int kk = 0; kk < 4; ++kk) {
      float4 w = Wl4[(k4 * 4 + kk) * 4 + c4];
      acc.x += av[kk] * w.x;
      acc.y += av[kk] * w.y;
      acc.z += av[kk] * w.z;
      acc.w += av[kk] * w.w;
    }
  }
  acc.x += bl[c4 * 4 + 0];
  acc.y += bl[c4 * 4 + 1];
  acc.z += bl[c4 * 4 + 2];
  acc.w += bl[c4 * 4 + 3];
  ((float4*)out)[row * 4 + c4] = acc;
}

extern "C" void kernel_launch(void* const* d_in, const int* in_sizes, int n_in,
                              void* d_out, int out_size, void* d_ws, size_t ws_size,
                              hipStream_t stream) {
  const float* x_paper = (const float*)d_in[0];
  const float* x_author = (const float*)d_in[1];
  // d_in[2] x_field: DEAD (fields never feed papers/authors; output = papers only)
  const float* Wp0 = (const float*)d_in[3];
  const float* Wp1 = (const float*)d_in[4];
  const float* Wa0 = (const float*)d_in[5];
  const float* Wa1 = (const float*)d_in[6];
  // d_in[7] W_field_0, d_in[8] W_field_1: DEAD
  const float* Wout = (const float*)d_in[9];
  const float* bout = (const float*)d_in[10];
  const int* src_w = (const int*)d_in[11];
  const int* dst_w = (const int*)d_in[12];
  const int* src_b = (const int*)d_in[13];
  const int* dst_b = (const int*)d_in[14];
  const int* src_c = (const int*)d_in[15];
  const int* dst_c = (const int*)d_in[16];
  // d_in[17]/d_in[18] topic edges: DEAD

  const int NP = in_sizes[0] / 128, NA = in_sizes[1] / 128;
  const int EW = in_sizes[11], EB = in_sizes[13], EC = in_sizes[15];

  // ---- workspace layout (~122 MB) ----
  float* gp = (float*)d_ws;                        // [NP,128] f32 gather out (papers)
  float* ga = gp + (size_t)NP * 128;               // [NA,128] f32 gather out (authors)
  ushort* hbp = (ushort*)(ga + (size_t)NA * 128);  // [NP,128] bf16 h (papers)
  ushort* hba = hbp + (size_t)NP * 128;            // [NA,128] bf16 h (authors)
  int* rs_w = (int*)(hba + (size_t)NA * 128);      // [NP+1]
  int* rs_c = rs_w + (NP + 1);                     // [NP+1]
  int* rs_b = rs_c + (NP + 1);                     // [NA+1]
  int* col_w = rs_b + (NA + 1);                    // [EW]
  int* col_c = col_w + EW;                         // [EC]
  int* col_b = col_c + EC;                         // [EB]
  // bf16-transposed weights, 256B-aligned: 4 x 32KB
  ushort* wt0 = (ushort*)(((uintptr_t)(col_b + EB) + 255) & ~(uintptr_t)255);
  ushort* wt1 = wt0 + 128 * 128;
  ushort* wt2 = wt1 + 128 * 128;
  ushort* wt3 = wt2 + 128 * 128;
  // transient CSR-build scratch aliased into gp/ga (CSR build finishes before gathers)
  int* cnt_w = (int*)gp;       // [NP]
  int* cnt_c = cnt_w + NP;     // [NP]
  int* cnt_b = cnt_c + NP;     // [NA]
  int* bs_w = (int*)ga;        // [1024]
  int* bs_c = bs_w + 1024;     // [1024]
  int* bs_b = bs_c + 1024;     // [1024]

  dim3 B(256);
  auto cdiv = [](long a, long b) { return (int)((a + b - 1) / b); };
  const int nbw = cdiv(NP, 256), nbc = cdiv(NP, 256), nbb = cdiv(NA, 256);
  const long ET = (long)EW + EC + EB;

  // ---- CSR build (graphs layer-invariant; build once, use twice) ----
  hipMemsetAsync(cnt_w, 0, (size_t)(2 * NP + NA) * 4, stream);
  count3_kernel<<<cdiv(ET, 256), B, 0, stream>>>(dst_w, EW, cnt_w, dst_c, EC, cnt_c,
                                                 dst_b, EB, cnt_b);
  scan3_kernel<<<nbw + nbc + nbb, B, 0, stream>>>(cnt_w, NP, rs_w, bs_w, cnt_c, NP, rs_c,
                                                  bs_c, cnt_b, NA, rs_b, bs_b, nbw, nbc);
  bsum3_kernel<<<3, 1024, 0, stream>>>(bs_w, nbw, bs_c, nbc, bs_b, nbb);
  addoff3_kernel<<<cdiv((long)(NP + 1) * 2 + NA + 1, 256), B, 0, stream>>>(
      rs_w, NP, bs_w, rs_c, NP, bs_c, rs_b, NA, bs_b);
  hipMemsetAsync(cnt_w, 0, (size_t)(2 * NP + NA) * 4, stream);
  scatter3_kernel<<<cdiv(ET, 256), B, 0, stream>>>(
      src_w, dst_w, EW, rs_w, cnt_w, col_w, src_c, dst_c, EC, rs_c, cnt_c, col_c,
      src_b, dst_b, EB, rs_b, cnt_b, col_b);

  // ---- weight prep: bf16 transposed ----
  prep_w_kernel<<<dim3(64, 4), B, 0, stream>>>(Wp0, Wa0, Wp1, Wa1, wt0, wt1, wt2, wt3);

  // ---- layer 0: h = relu(x @ W0) -> bf16 (paper+author in one dispatch) ----
  gemm_mfma_kernel<<<cdiv(NP, 64) + cdiv(NA, 64), B, 0, stream>>>(
      x_paper, wt0, hbp, NP, x_author, wt1, hba, NA);

  // ---- layer 0 fused gather+combine (bf16 in, f32 out) ----
  gather_paper_kernel<<<cdiv(NP, 4), B, 0, stream>>>(hbp, hba, rs_w, col_w, rs_c, col_c,
                                                     gp, NP);
  gather_author_kernel<<<cdiv(NA, 4), B, 0, stream>>>(hba, hbp, rs_b, col_b, ga, NA);

  // ---- layer 1 GEMMs (read f32 gather outputs, write bf16 h) ----
  gemm_mfma_kernel<<<cdiv(NP, 64) + cdiv(NA, 64), B, 0, stream>>>(
      gp, wt2, hbp, NP, ga, wt3, hba, NA);

  // ---- layer 1 fused gather (papers only; author/field outputs are dead) ----
  gather_paper_kernel<<<cdiv(NP, 4), B, 0, stream>>>(hbp, hba, rs_w, col_w, rs_c, col_c,
                                                     gp, NP);

  // ---- final: out = gp @ W_out + b_out ----
  final_kernel<<<cdiv(NP, 64), B, 0, stream>>>(gp, Wout, bout, (float*)d_out, NP);
}